// Round 3
// baseline (489.593 us; speedup 1.0000x reference)
//
#include <hip/hip_runtime.h>
#include <cstdint>

// Static problem sizes
#define BB 32
#define CC 512
#define NSQ 4096      // N*N
#define SS 128
#define MM 256
#define PP 2080
#define JJ (BB*PP)    // 66560
#define NBIG (JJ/128) // 520 big blocks

// ws layout (byte offsets)
#define WS_SN     0         // sents_norm fp32: 128*512*4 = 262144
#define WS_SNB    262144    // sents_norm bf16: 128*512*2 = 131072
#define WS_IDX    393216    // idx: 2080 i32 = 8320
#define WS_IV     401536    // iv_all: 256*128*4 = 131072
#define WS_NEGQ   532608    // neg_sum_q: 128*4 = 512

typedef short bf16x8 __attribute__((ext_vector_type(8)));   // 8 bf16 raw (4 VGPRs)
typedef float f32x4  __attribute__((ext_vector_type(4)));   // MFMA accumulator

__device__ __forceinline__ unsigned short f2bf(float x) {
    unsigned int u = __float_as_uint(x);
    unsigned int r = (u + 0x7fffu + ((u >> 16) & 1u)) >> 16;   // RNE
    return (unsigned short)r;
}

// ---------------------------------------------------------------------------
// prep: blocks 0..127 normalize sents rows (fp32 + bf16 copies);
//       128..143 build idx table; 144 zeroes negq.
__global__ void k_prep(const float* __restrict__ sents, float* __restrict__ sn,
                       unsigned short* __restrict__ snb,
                       int* __restrict__ idx, float* __restrict__ negq) {
    const int blk = blockIdx.x, t = threadIdx.x;
    if (blk < 128) {
        __shared__ float red[256];
        const float* row = sents + (size_t)blk * CC;
        float x0 = row[t], x1 = row[t + 256];
        red[t] = x0 * x0 + x1 * x1;
        __syncthreads();
        for (int off = 128; off > 0; off >>= 1) {
            if (t < off) red[t] += red[t + off];
            __syncthreads();
        }
        float rn = 1.0f / fmaxf(sqrtf(red[0]), 1e-12f);
        float y0 = x0 * rn, y1 = x1 * rn;
        sn[(size_t)blk * CC + t]        = y0;
        sn[(size_t)blk * CC + t + 256]  = y1;
        snb[(size_t)blk * CC + t]       = f2bf(y0);
        snb[(size_t)blk * CC + t + 256] = f2bf(y1);
    } else if (blk < 144) {
        int i = (blk - 128) * 256 + t;      // 0..4095
        int r = i >> 6, c = i & 63;
        if (c >= r) {
            int p = r * 64 - (r * (r - 1)) / 2 + (c - r);
            idx[p] = i;
        }
    } else {
        if (t < 128) negq[t] = 0.0f;
    }
}

// ---------------------------------------------------------------------------
// Mega kernel. Blocks 0..255: per-target path (argmax + gather + iv row).
// Blocks 256..775: 128x128 MFMA score tile -> masked exp-sum into negq.
//
// LDS swizzle for the GEMM tiles: element (row, k) of a 128x64 bf16 tile is
// stored at row*64 + ((k/8) ^ (row&7))*8 + k%8. ds_write_b128 staging then
// lands each 8-lane group on all 32 banks (conflict-free), and MFMA frag
// reads are 2-way aliased only (free per m136).

union SMem {
    struct {
        unsigned short sA[128 * 64];   // 16 KB sents tile  [row][kswz]
        unsigned short vB[128 * 64];   // 16 KB video tile  [col][kswz]
        int   colb[128];
        int   colflat[128];
        float colrn[128];
        float sqpart[256];
    } big;                             // ~35.3 KB
    struct {
        float sv[256];
        int   si[256];
        float tvs[512];
        float red[256];
    } fus;                             // 5 KB
};

__global__ __launch_bounds__(256, 4)
void k_mega(const float* __restrict__ video, const float* __restrict__ sn,
            const unsigned short* __restrict__ snb,
            const float* __restrict__ iou2d, const float* __restrict__ iou2ds,
            const int* __restrict__ idx,
            float* __restrict__ iv, float* __restrict__ negq) {
    __shared__ SMem sm;
    const int t = threadIdx.x;

    if (blockIdx.x < MM) {
        // ---------------- fused per-target path ----------------
        const int m = blockIdx.x;
        // argmax of iou2ds[m] over valid proposals (tie -> lowest p)
        {
            float best = -1e30f; int bi = 1 << 30;
            const float* row = iou2ds + (size_t)m * NSQ;
            for (int p = t; p < PP; p += 256) {
                float v = row[idx[p]];
                if (v > best || (v == best && p < bi)) { best = v; bi = p; }
            }
            sm.fus.sv[t] = best; sm.fus.si[t] = bi;
            __syncthreads();
            for (int off = 128; off > 0; off >>= 1) {
                if (t < off) {
                    float v2 = sm.fus.sv[t + off]; int i2 = sm.fus.si[t + off];
                    if (v2 > sm.fus.sv[t] || (v2 == sm.fus.sv[t] && i2 < sm.fus.si[t])) {
                        sm.fus.sv[t] = v2; sm.fus.si[t] = i2;
                    }
                }
                __syncthreads();
            }
        }
        const int flat = idx[sm.fus.si[0]];
        const int b = m >> 3;                     // scatter_m2v

        // gather + normalize the top column
        const float* base = video + (size_t)b * CC * NSQ + flat;
        float x0 = base[(size_t)t * NSQ];
        float x1 = base[(size_t)(t + 256) * NSQ];
        sm.fus.red[t] = x0 * x0 + x1 * x1;
        __syncthreads();
        for (int off = 128; off > 0; off >>= 1) {
            if (t < off) sm.fus.red[t] += sm.fus.red[t + off];
            __syncthreads();
        }
        float rn = 1.0f / fmaxf(sqrtf(sm.fus.red[0]), 1e-12f);
        sm.fus.tvs[t] = x0 * rn;
        sm.fus.tvs[t + 256] = x1 * rn;
        __syncthreads();

        // iv row: thread (s = t&127, h = t>>7) computes half-dot
        const int s = t & 127, h = t >> 7;
        const float4* a4 = (const float4*)(sm.fus.tvs + h * 256);
        const float4* b4 = (const float4*)(sn + (size_t)s * CC + h * 256);
        float acc = 0.f;
#pragma unroll 8
        for (int c = 0; c < 64; c++) {
            float4 a = a4[c], bb = b4[c];
            acc += a.x * bb.x + a.y * bb.y + a.z * bb.z + a.w * bb.w;
        }
        __syncthreads();
        sm.fus.red[t] = acc;
        __syncthreads();
        if (t < 128) iv[(size_t)m * SS + t] = sm.fus.red[t] + sm.fus.red[t + 128];
        return;
    }

    // ---------------- big MFMA path ----------------
    const int w    = t >> 6;          // wave 0..3
    const int lane = t & 63;
    const int q    = lane >> 4;       // quad 0..3
    const int l15  = lane & 15;
    const int j0   = (blockIdx.x - MM) * 128;

    if (t < 128) {
        int col = j0 + t;
        int b = col / PP;
        sm.big.colb[t] = b;
        sm.big.colflat[t] = idx[col - b * PP];
    }

    // loader identity: column jj, k-half kh (32 channels each)
    const int jj = t & 127;
    const int kh = t >> 7;
    int colL = j0 + jj;
    int bL = colL / PP;
    int flatL = idx[colL - bL * PP];
    const float* vbase = video + (size_t)bL * (CC * NSQ) + flatL;

    f32x4 acc[2][8];
#pragma unroll
    for (int i = 0; i < 2; i++)
#pragma unroll
        for (int j = 0; j < 8; j++) acc[i][j] = (f32x4){0.f, 0.f, 0.f, 0.f};

    float sqa = 0.f;
    const int swzA_w = jj & 7;        // row&7 for the A-stage writer below uses row
    (void)swzA_w;

    for (int k0 = 0; k0 < CC; k0 += 64) {
        __syncthreads();
        // stage A: 128 rows x 64 k of bf16 sents (swizzled store)
#pragma unroll
        for (int it = 0; it < 4; it++) {
            int lin = t + it * 256;
            int row = lin >> 3, G = lin & 7;
            bf16x8 v = *(const bf16x8*)(snb + (size_t)row * CC + k0 + G * 8);
            *(bf16x8*)(sm.big.sA + row * 64 + ((G ^ (row & 7)) * 8)) = v;
        }
        // stage B: 128 cols x 64 k, fp32 gather -> bf16, fused sumsq, swizzled store
        {
            const float* vp = vbase + (size_t)(k0 + kh * 32) * NSQ;
#pragma unroll
            for (int g = 0; g < 4; g++) {
                unsigned short buf[8];
#pragma unroll
                for (int i = 0; i < 8; i++) {
                    float x = vp[(size_t)(g * 8 + i) * NSQ];
                    sqa += x * x;
                    buf[i] = f2bf(x);
                }
                int G = kh * 4 + g;
                *(bf16x8*)(sm.big.vB + jj * 64 + ((G ^ (jj & 7)) * 8)) = *(bf16x8*)buf;
            }
        }
        __syncthreads();
        // compute: two K=32 sub-steps
#pragma unroll
        for (int ks = 0; ks < 64; ks += 32) {
            const int so = ((q + (ks >> 3)) ^ (l15 & 7)) * 8;   // swizzled k-offset
            bf16x8 a[2], bfr[8];
#pragma unroll
            for (int rt = 0; rt < 2; rt++) {
                int row = w * 32 + rt * 16 + l15;
                a[rt] = *(const bf16x8*)(sm.big.sA + row * 64 + so);
            }
#pragma unroll
            for (int ct = 0; ct < 8; ct++) {
                int col = ct * 16 + l15;
                bfr[ct] = *(const bf16x8*)(sm.big.vB + col * 64 + so);
            }
#pragma unroll
            for (int rt = 0; rt < 2; rt++)
#pragma unroll
                for (int ct = 0; ct < 8; ct++)
                    acc[rt][ct] = __builtin_amdgcn_mfma_f32_16x16x32_bf16(
                        a[rt], bfr[ct], acc[rt][ct], 0, 0, 0);
        }
    }

    // column reciprocal norms (fp32)
    sm.big.sqpart[t] = sqa;
    __syncthreads();
    if (t < 128)
        sm.big.colrn[t] = 1.0f / fmaxf(sqrtf(sm.big.sqpart[t] + sm.big.sqpart[t + 128]), 1e-12f);
    __syncthreads();

    // epilogue: scale, exp, mask, 16-lane butterfly reduce, atomicAdd
    // D layout: row = w*32 + rt*16 + q*4 + reg, col = ct*16 + l15
#pragma unroll
    for (int rt = 0; rt < 2; rt++) {
#pragma unroll
        for (int r = 0; r < 4; r++) {
            int s = w * 32 + rt * 16 + q * 4 + r;
            float rowsum = 0.f;
#pragma unroll
            for (int ct = 0; ct < 8; ct++) {
                int c = ct * 16 + l15;
                float sc = acc[rt][ct][r] * sm.big.colrn[c];
                float e = __expf(sc * 10.0f);          // / T_TEMP
                if ((s >> 2) == sm.big.colb[c]) {      // same-video block
                    if (iou2d[(size_t)s * NSQ + sm.big.colflat[c]] > 0.5f) e = 0.f;
                }
                rowsum += e;
            }
#pragma unroll
            for (int msk = 1; msk < 16; msk <<= 1)
                rowsum += __shfl_xor(rowsum, msk, 64);
            if (l15 == 0) atomicAdd(&negq[s], rowsum);
        }
    }
}

// ---------------------------------------------------------------------------
// final losses
__global__ void k_final(const float* __restrict__ iv, const float* __restrict__ negq,
                        float* __restrict__ out) {
    const int t = threadIdx.x;   // 256 = M
    __shared__ float rv[256], rq[256];
    const float* row = iv + (size_t)t * SS;
    const int ms = t >> 1;       // scatter_m2s
    float pos = row[ms];
    float nv = 0.f;
    for (int s = 0; s < SS; s++) {
        float e = expf(row[s] * 10.0f);
        if (s == ms) e = 0.f;
        nv += e;
    }
    float pe = expf(pos * 10.0f);
    float lv = logf(pe + nv) - pos * 10.0f;
    float lq = logf(pe + negq[ms]) - pos * 10.0f;
    rv[t] = lv; rq[t] = lq;
    __syncthreads();
    for (int off = 128; off > 0; off >>= 1) {
        if (t < off) { rv[t] += rv[t + off]; rq[t] += rq[t + off]; }
        __syncthreads();
    }
    if (t == 0) {
        float liv = rv[0] / 256.f, liq = rq[0] / 256.f;
        out[0] = liv + liq;   // total (WEIGHT=1)
        out[1] = liv;
        out[2] = liq;
    }
}

// ---------------------------------------------------------------------------
extern "C" void kernel_launch(void* const* d_in, const int* in_sizes, int n_in,
                              void* d_out, int out_size, void* d_ws, size_t ws_size,
                              hipStream_t stream) {
    const float* video  = (const float*)d_in[0];   // (B,C,N,N)
    const float* sents  = (const float*)d_in[1];   // (S,C)
    const float* iou2d  = (const float*)d_in[4];   // (S,N,N)
    const float* iou2ds = (const float*)d_in[5];   // (M,N,N)
    float* out = (float*)d_out;

    char* ws = (char*)d_ws;
    float*          sn   = (float*)(ws + WS_SN);
    unsigned short* snb  = (unsigned short*)(ws + WS_SNB);
    int*            idx  = (int*)(ws + WS_IDX);
    float*          iv   = (float*)(ws + WS_IV);
    float*          negq = (float*)(ws + WS_NEGQ);

    k_prep <<<145, 256, 0, stream>>>(sents, sn, snb, idx, negq);
    k_mega <<<MM + NBIG, 256, 0, stream>>>(video, sn, snb, iou2d, iou2ds, idx, iv, negq);
    k_final<<<1, 256, 0, stream>>>(iv, negq, out);
}

// Round 4
// 481.193 us; speedup vs baseline: 1.0175x; 1.0175x over previous
//
#include <hip/hip_runtime.h>
#include <cstdint>

// Static problem sizes
#define BB 32
#define CC 512
#define NSQ 4096      // N*N
#define SS 128
#define MM 256
#define PP 2080
#define JJ (BB*PP)    // 66560
#define NBIG (JJ/128) // 520 big blocks

// ws layout (byte offsets)
#define WS_SN     0         // sents_norm fp32: 128*512*4 = 262144
#define WS_SNB    262144    // sents_norm bf16: 128*512*2 = 131072
#define WS_IDX    393216    // idx: 2080 i32 = 8320
#define WS_IV     401536    // iv_all: 256*128*4 = 131072
#define WS_PART   532608    // negq partials: 520*128*4 = 266240

typedef short bf16x8 __attribute__((ext_vector_type(8)));   // 8 bf16 raw (4 VGPRs)
typedef float f32x4  __attribute__((ext_vector_type(4)));   // MFMA accumulator

__device__ __forceinline__ unsigned short f2bf(float x) {
    unsigned int u = __float_as_uint(x);
    unsigned int r = (u + 0x7fffu + ((u >> 16) & 1u)) >> 16;   // RNE
    return (unsigned short)r;
}

// ---------------------------------------------------------------------------
// prep: blocks 0..127 normalize sents rows (fp32 + bf16); 128..143 idx table.
__global__ void k_prep(const float* __restrict__ sents, float* __restrict__ sn,
                       unsigned short* __restrict__ snb, int* __restrict__ idx) {
    const int blk = blockIdx.x, t = threadIdx.x;
    if (blk < 128) {
        __shared__ float red[256];
        const float* row = sents + (size_t)blk * CC;
        float x0 = row[t], x1 = row[t + 256];
        red[t] = x0 * x0 + x1 * x1;
        __syncthreads();
        for (int off = 128; off > 0; off >>= 1) {
            if (t < off) red[t] += red[t + off];
            __syncthreads();
        }
        float rn = 1.0f / fmaxf(sqrtf(red[0]), 1e-12f);
        float y0 = x0 * rn, y1 = x1 * rn;
        sn[(size_t)blk * CC + t]        = y0;
        sn[(size_t)blk * CC + t + 256]  = y1;
        snb[(size_t)blk * CC + t]       = f2bf(y0);
        snb[(size_t)blk * CC + t + 256] = f2bf(y1);
    } else {
        int i = (blk - 128) * 256 + t;      // 0..4095
        int r = i >> 6, c = i & 63;
        if (c >= r) {
            int p = r * 64 - (r * (r - 1)) / 2 + (c - r);
            idx[p] = i;
        }
    }
}

// ---------------------------------------------------------------------------
// Mega kernel. Blocks 0..255: per-target path (argmax + gather + iv row).
// Blocks 256..775: 128x128 MFMA score tile -> masked exp-sums -> part[j][s].
//
// LDS swizzle: element (row,k) of a 128x64 bf16 tile stored at
// row*64 + ((k/8) ^ (row&7))*8 + k%8. Staging ds_write_b128 and frag
// ds_read_b128 both land balanced across the 32 banks.

union SMem {
    struct {
        unsigned short sA[128 * 64];   // 16 KB sents tile  [row][kswz]
        unsigned short vB[128 * 64];   // 16 KB video tile  [col][kswz]
        int   colb[128];
        int   colflat[128];
        float colrn[128];
        float sqpart[256];
    } big;                             // ~34.6 KB
    struct {
        float sv[256];
        int   si[256];
        float tvs[512];
        float red[256];
    } fus;                             // 5 KB
};

__global__ __launch_bounds__(256, 2)   // 256 unified regs/wave: no spill
void k_mega(const float* __restrict__ video, const float* __restrict__ sn,
            const unsigned short* __restrict__ snb,
            const float* __restrict__ iou2d, const float* __restrict__ iou2ds,
            const int* __restrict__ idx,
            float* __restrict__ iv, float* __restrict__ part) {
    __shared__ SMem sm;
    const int t = threadIdx.x;

    if (blockIdx.x < MM) {
        // ---------------- fused per-target path ----------------
        const int m = blockIdx.x;
        {   // argmax of iou2ds[m] over valid proposals (tie -> lowest p)
            float best = -1e30f; int bi = 1 << 30;
            const float* row = iou2ds + (size_t)m * NSQ;
            for (int p = t; p < PP; p += 256) {
                float v = row[idx[p]];
                if (v > best || (v == best && p < bi)) { best = v; bi = p; }
            }
            sm.fus.sv[t] = best; sm.fus.si[t] = bi;
            __syncthreads();
            for (int off = 128; off > 0; off >>= 1) {
                if (t < off) {
                    float v2 = sm.fus.sv[t + off]; int i2 = sm.fus.si[t + off];
                    if (v2 > sm.fus.sv[t] || (v2 == sm.fus.sv[t] && i2 < sm.fus.si[t])) {
                        sm.fus.sv[t] = v2; sm.fus.si[t] = i2;
                    }
                }
                __syncthreads();
            }
        }
        const int flat = idx[sm.fus.si[0]];
        const int b = m >> 3;                     // scatter_m2v

        // gather + normalize the top column
        const float* base = video + (size_t)b * CC * NSQ + flat;
        float x0 = base[(size_t)t * NSQ];
        float x1 = base[(size_t)(t + 256) * NSQ];
        sm.fus.red[t] = x0 * x0 + x1 * x1;
        __syncthreads();
        for (int off = 128; off > 0; off >>= 1) {
            if (t < off) sm.fus.red[t] += sm.fus.red[t + off];
            __syncthreads();
        }
        float rn = 1.0f / fmaxf(sqrtf(sm.fus.red[0]), 1e-12f);
        sm.fus.tvs[t] = x0 * rn;
        sm.fus.tvs[t + 256] = x1 * rn;
        __syncthreads();

        // iv row: thread (s = t&127, h = t>>7) computes half-dot
        const int s = t & 127, h = t >> 7;
        const float4* a4 = (const float4*)(sm.fus.tvs + h * 256);
        const float4* b4 = (const float4*)(sn + (size_t)s * CC + h * 256);
        float acc = 0.f;
#pragma unroll 8
        for (int c = 0; c < 64; c++) {
            float4 a = a4[c], bb = b4[c];
            acc += a.x * bb.x + a.y * bb.y + a.z * bb.z + a.w * bb.w;
        }
        __syncthreads();
        sm.fus.red[t] = acc;
        __syncthreads();
        if (t < 128) iv[(size_t)m * SS + t] = sm.fus.red[t] + sm.fus.red[t + 128];
        return;
    }

    // ---------------- big MFMA path ----------------
    const int w    = t >> 6;          // wave 0..3
    const int lane = t & 63;
    const int q    = lane >> 4;       // quad 0..3
    const int l15  = lane & 15;
    const int bid  = blockIdx.x - MM; // 0..519
    const int j0   = bid * 128;

    if (t < 128) {
        int col = j0 + t;
        int b = col / PP;
        sm.big.colb[t] = b;
        sm.big.colflat[t] = idx[col - b * PP];
    }

    // loader identities
    const int G_    = t & 7;          // A-stage k-group (same for all its)
    const int rowA0 = t >> 3;         // A-stage base row (stride 32 per it)
    const int swzA  = ((G_ ^ (rowA0 & 7)) * 8);
    const int jj = t & 127;
    const int kh = t >> 7;
    int colL = j0 + jj;
    int bL = colL / PP;
    int flatL = idx[colL - bL * PP];
    const float* vbase = video + (size_t)bL * (CC * NSQ) + flatL
                               + (size_t)(kh * 32) * NSQ;
    const unsigned short* snbA = snb + (size_t)rowA0 * CC + G_ * 8;
    unsigned short* sAp = sm.big.sA + rowA0 * 64 + swzA;
    unsigned short* vBp = sm.big.vB + jj * 64;
    const int jj7 = jj & 7;

    // register prefetch buffers (double-buffered across K-iterations)
    bf16x8 prA[4];
    float  pr[32];
#pragma unroll
    for (int it = 0; it < 4; it++)
        prA[it] = *(const bf16x8*)(snbA + (size_t)it * 32 * CC);
#pragma unroll
    for (int i = 0; i < 32; i++) pr[i] = vbase[(size_t)i * NSQ];

    f32x4 acc[2][8];
#pragma unroll
    for (int i = 0; i < 2; i++)
#pragma unroll
        for (int j = 0; j < 8; j++) acc[i][j] = (f32x4){0.f, 0.f, 0.f, 0.f};

    float sqa = 0.f;

    for (int k0 = 0; k0 < CC; k0 += 64) {
        // write phase (consumes prefetch registers)
#pragma unroll
        for (int it = 0; it < 4; it++)
            *(bf16x8*)(sAp + it * 32 * 64) = prA[it];
#pragma unroll
        for (int g = 0; g < 4; g++) {
            unsigned short buf[8];
#pragma unroll
            for (int i = 0; i < 8; i++) {
                float x = pr[g * 8 + i];
                sqa += x * x;
                buf[i] = f2bf(x);
            }
            int Gb = kh * 4 + g;
            *(bf16x8*)(vBp + ((Gb ^ jj7) * 8)) = *(bf16x8*)buf;
        }
        __syncthreads();

        // issue next iteration's global loads: in flight during MFMA+barrier
        if (k0 + 64 < CC) {
            const int kn = k0 + 64;
#pragma unroll
            for (int it = 0; it < 4; it++)
                prA[it] = *(const bf16x8*)(snbA + (size_t)it * 32 * CC + kn);
            const float* vp = vbase + (size_t)kn * NSQ;
#pragma unroll
            for (int i = 0; i < 32; i++) pr[i] = vp[(size_t)i * NSQ];
        }

        // compute: two K=32 sub-steps
#pragma unroll
        for (int ks = 0; ks < 64; ks += 32) {
            const int so = (((ks >> 3) + q) ^ (l15 & 7)) * 8;   // swizzled k-offset
            bf16x8 a[2], bfr[8];
#pragma unroll
            for (int rt = 0; rt < 2; rt++) {
                int row = w * 32 + rt * 16 + l15;
                a[rt] = *(const bf16x8*)(sm.big.sA + row * 64 + so);
            }
#pragma unroll
            for (int ct = 0; ct < 8; ct++) {
                int col = ct * 16 + l15;
                bfr[ct] = *(const bf16x8*)(sm.big.vB + col * 64 + so);
            }
#pragma unroll
            for (int rt = 0; rt < 2; rt++)
#pragma unroll
                for (int ct = 0; ct < 8; ct++)
                    acc[rt][ct] = __builtin_amdgcn_mfma_f32_16x16x32_bf16(
                        a[rt], bfr[ct], acc[rt][ct], 0, 0, 0);
        }
        __syncthreads();
    }

    // column reciprocal norms (fp32)
    sm.big.sqpart[t] = sqa;
    __syncthreads();
    if (t < 128)
        sm.big.colrn[t] = 1.0f / fmaxf(sqrtf(sm.big.sqpart[t] + sm.big.sqpart[t + 128]), 1e-12f);
    __syncthreads();

    // epilogue: hoist per-column data, then scale/exp/mask/reduce
    float crn[8]; int cb[8], cf[8];
#pragma unroll
    for (int ct = 0; ct < 8; ct++) {
        int c = ct * 16 + l15;
        crn[ct] = sm.big.colrn[c];
        cb[ct]  = sm.big.colb[c];
        cf[ct]  = sm.big.colflat[c];
    }
    // D layout: row = w*32 + rt*16 + q*4 + reg, col = ct*16 + l15
#pragma unroll
    for (int rt = 0; rt < 2; rt++) {
#pragma unroll
        for (int r = 0; r < 4; r++) {
            int s = w * 32 + rt * 16 + q * 4 + r;
            float rowsum = 0.f;
#pragma unroll
            for (int ct = 0; ct < 8; ct++) {
                float sc = acc[rt][ct][r] * crn[ct];
                float e = __expf(sc * 10.0f);          // / T_TEMP
                if ((s >> 2) == cb[ct]) {              // same-video block
                    if (iou2d[(size_t)s * NSQ + cf[ct]] > 0.5f) e = 0.f;
                }
                rowsum += e;
            }
#pragma unroll
            for (int msk = 1; msk < 16; msk <<= 1)
                rowsum += __shfl_xor(rowsum, msk, 64);
            if (l15 == 0) part[(size_t)bid * 128 + s] = rowsum;   // plain store
        }
    }
}

// ---------------------------------------------------------------------------
// final: reduce per-block partials -> negq, then both losses.
__global__ void k_final(const float* __restrict__ iv, const float* __restrict__ part,
                        float* __restrict__ out) {
    const int t = threadIdx.x;   // 256 = M
    __shared__ float nqs[256];
    __shared__ float rv[256], rq[256];
    {   // negq[s] partial reduce: thread (s=t&127, h=t>>7) sums half the blocks
        const int sl = t & 127, h = t >> 7;
        float nq = 0.f;
        for (int j = h; j < NBIG; j += 2) nq += part[(size_t)j * 128 + sl];
        nqs[t] = nq;
    }
    __syncthreads();
    const float* row = iv + (size_t)t * SS;
    const int ms = t >> 1;       // scatter_m2s
    float pos = row[ms];
    float nv = 0.f;
    for (int s = 0; s < SS; s++) {
        float e = expf(row[s] * 10.0f);
        if (s == ms) e = 0.f;
        nv += e;
    }
    float pe = expf(pos * 10.0f);
    float negq_ms = nqs[ms] + nqs[ms + 128];
    float lv = logf(pe + nv) - pos * 10.0f;
    float lq = logf(pe + negq_ms) - pos * 10.0f;
    rv[t] = lv; rq[t] = lq;
    __syncthreads();
    for (int off = 128; off > 0; off >>= 1) {
        if (t < off) { rv[t] += rv[t + off]; rq[t] += rq[t + off]; }
        __syncthreads();
    }
    if (t == 0) {
        float liv = rv[0] / 256.f, liq = rq[0] / 256.f;
        out[0] = liv + liq;   // total (WEIGHT=1)
        out[1] = liv;
        out[2] = liq;
    }
}

// ---------------------------------------------------------------------------
extern "C" void kernel_launch(void* const* d_in, const int* in_sizes, int n_in,
                              void* d_out, int out_size, void* d_ws, size_t ws_size,
                              hipStream_t stream) {
    const float* video  = (const float*)d_in[0];   // (B,C,N,N)
    const float* sents  = (const float*)d_in[1];   // (S,C)
    const float* iou2d  = (const float*)d_in[4];   // (S,N,N)
    const float* iou2ds = (const float*)d_in[5];   // (M,N,N)
    float* out = (float*)d_out;

    char* ws = (char*)d_ws;
    float*          sn   = (float*)(ws + WS_SN);
    unsigned short* snb  = (unsigned short*)(ws + WS_SNB);
    int*            idx  = (int*)(ws + WS_IDX);
    float*          iv   = (float*)(ws + WS_IV);
    float*          part = (float*)(ws + WS_PART);

    k_prep <<<144, 256, 0, stream>>>(sents, sn, snb, idx);
    k_mega <<<MM + NBIG, 256, 0, stream>>>(video, sn, snb, iou2d, iou2ds, idx, iv, part);
    k_final<<<1, 256, 0, stream>>>(iv, part, out);
}